// Round 15
// baseline (319.785 us; speedup 1.0000x reference)
//
#include <hip/hip_runtime.h>

#define BB 2
#define CC 2
#define NN 1024
#define HH 8
#define BCHN 32
#define SVN  (BCHN*NN)       // 32768
#define LOG2E 1.44269504f
#define NBLK 512

typedef _Float16 f16x8 __attribute__((ext_vector_type(8)));
typedef _Float16 f16x4 __attribute__((ext_vector_type(4)));
typedef __fp16 h16x2 __attribute__((ext_vector_type(2)));   // cvt_pkrtz native type
typedef float f32x4 __attribute__((ext_vector_type(4)));

__device__ __forceinline__ float fexp2(float x) {
  float r; asm("v_exp_f32 %0, %1" : "=v"(r) : "v"(x)); return r;
}

// Direct global->LDS staging. LDS dest = wave-uniform base + lane*16B; global src per-lane.
__device__ __forceinline__ void gl_lds16(const _Float16* g, _Float16* l) {
  __builtin_amdgcn_global_load_lds(
      (const __attribute__((address_space(1))) void*)g,
      (__attribute__((address_space(3))) void*)l, 16, 0, 0);
}

// R1-PROVEN grid barrier (passed correctness at 512x256 on this problem).
// Monotonic counter: g-th barrier waits for g*NBLK arrivals. Bounded spin.
__device__ __forceinline__ void gbar(unsigned* cnt, unsigned* gen, unsigned g) {
  __syncthreads();                 // drains vmcnt/lgkmcnt for all waves
  if (threadIdx.x == 0) {
    __threadfence();               // release: L2 writeback (cross-XCD visibility)
    if (atomicAdd(cnt, 1u) == g*(unsigned)NBLK - 1u) atomicAdd(gen, 1u);
    int guard = 0;
    while (__hip_atomic_load(gen, __ATOMIC_RELAXED, __HIP_MEMORY_SCOPE_AGENT) < g) {
      __builtin_amdgcn_s_sleep(8);
      if (++guard > (1 << 20)) break;
    }
    __threadfence();               // acquire: invalidate stale L1/L2
  }
  __syncthreads();
}

// Hp/w2T tiles are 4KB [64 f][32 k] with PERMUTED in-tile order:
//   16B-chunk(f,k) = (f>>4)*64 + ((k>>3)&3)*16 + (f&15), elem j = k&7.
// => MFMA fragment read for (ft, lane) is chunk ft*64 + lane: lane-linear, 0 conflicts.

union SmemU {
  __align__(16) _Float16 tile[64*72];                  // w2T transpose staging (9.2 KB)
  struct { float sp[4][32]; float sd[4][32]; } pr;     // proj1 reductions (1 KB)
  struct {                                             // attn coop (29.8 KB)
    __align__(16) _Float16 stg[2][2048];
    __align__(16) float dstg[1024];
    float pw[4][16][68];
  } at;
  struct {                                             // proj2 coop (16 KB)
    __align__(16) _Float16 Ast[2][2048];
    __align__(16) _Float16 Bst[2][2048];
  } p2;
};

// ---------------- P1 unit: proj1 / w2T transpose / mask build (r13 proj1_fused body) ----
__device__ __forceinline__ void p1_unit(
    int u, const float* __restrict__ x, const int* __restrict__ adj,
    const float* __restrict__ w1, const float* __restrict__ w2,
    const float* __restrict__ asrc, const float* __restrict__ adst,
    _Float16* __restrict__ w2T, unsigned long long* __restrict__ bmg,
    _Float16* __restrict__ HpT, float* __restrict__ s_out, float* __restrict__ d_out,
    SmemU& sm)
{
  const int t = threadIdx.x;
  const int w = t >> 6, lane = t & 63;
  const int colr = lane & 15, quad = lane >> 4;

  if (u < 1024) {
    const int bch = u & 31;
    const int row0 = (u >> 5) * 32;
    const int h = bch & 7; const int bc = bch >> 3; const int c = bc & 1;

    const float* Ar0 = x + ((size_t)bc*NN + row0 + colr)*64;
    const float* Ar1 = Ar0 + (size_t)16*64;
    const float* Bw  = w1 + ((size_t)(c*HH + h))*64*64 + w*16 + colr;

    f32x4 acc0 = {0.f,0.f,0.f,0.f}, acc1 = {0.f,0.f,0.f,0.f};
    #pragma unroll
    for (int kb = 0; kb < 64; kb += 32) {
      const float4 pa0 = *(const float4*)(Ar0 + kb + quad*8);
      const float4 pa1 = *(const float4*)(Ar0 + kb + quad*8 + 4);
      const float4 pb0 = *(const float4*)(Ar1 + kb + quad*8);
      const float4 pb1 = *(const float4*)(Ar1 + kb + quad*8 + 4);
      float bv[8];
      #pragma unroll
      for (int j = 0; j < 8; ++j) bv[j] = Bw[(size_t)(kb + quad*8 + j)*64];
      f16x8 a0, a1, bf;
      a0[0]=(_Float16)pa0.x; a0[1]=(_Float16)pa0.y; a0[2]=(_Float16)pa0.z; a0[3]=(_Float16)pa0.w;
      a0[4]=(_Float16)pa1.x; a0[5]=(_Float16)pa1.y; a0[6]=(_Float16)pa1.z; a0[7]=(_Float16)pa1.w;
      a1[0]=(_Float16)pb0.x; a1[1]=(_Float16)pb0.y; a1[2]=(_Float16)pb0.z; a1[3]=(_Float16)pb0.w;
      a1[4]=(_Float16)pb1.x; a1[5]=(_Float16)pb1.y; a1[6]=(_Float16)pb1.z; a1[7]=(_Float16)pb1.w;
      #pragma unroll
      for (int j = 0; j < 8; ++j) bf[j] = (_Float16)bv[j];
      acc0 = __builtin_amdgcn_mfma_f32_16x16x32_f16(a0, bf, acc0, 0, 0, 0);
      acc1 = __builtin_amdgcn_mfma_f32_16x16x32_f16(a1, bf, acc1, 0, 0, 0);
    }

    const float af  = asrc[(c*HH + h)*64 + w*16 + colr];
    const float bf_ = adst[(c*HH + h)*64 + w*16 + colr];
    _Float16* HT = HpT + (size_t)bch*65536 + (size_t)(row0 >> 5)*2048;

    #pragma unroll
    for (int mt = 0; mt < 2; ++mt) {
      const f32x4 a = mt ? acc1 : acc0;
      f16x4 hv;
      #pragma unroll
      for (int i = 0; i < 4; ++i) {
        const float v = a[i];
        hv[i] = (_Float16)v;
        const float ex = __expf(2.f*v);
        const float th = 1.f - 2.f/(ex + 1.f);         // tanh(v)
        float ps = th * af, pd = th * bf_;
        #pragma unroll
        for (int off = 1; off < 16; off <<= 1) {
          ps += __shfl_xor(ps, off);
          pd += __shfl_xor(pd, off);
        }
        if (colr == 0) {
          sm.pr.sp[w][mt*16 + quad*4 + i] = ps;
          sm.pr.sd[w][mt*16 + quad*4 + i] = pd;
        }
      }
      const int chunk = w*64 + (mt*2 + (quad >> 1))*16 + colr;
      *(f16x4*)(HT + chunk*8 + (quad & 1)*4) = hv;
    }
    __syncthreads();
    if (t < 32) {
      const float sv = sm.pr.sp[0][t] + sm.pr.sp[1][t] + sm.pr.sp[2][t] + sm.pr.sp[3][t];
      const float dv = sm.pr.sd[0][t] + sm.pr.sd[1][t] + sm.pr.sd[2][t] + sm.pr.sd[3][t];
      s_out[bch*NN + row0 + t] = sv * LOG2E;
      d_out[bch*NN + row0 + t] = dv * LOG2E;
    }
  } else if (u < 1152) {
    const int uu0 = u - 1024;
    const int ch = uu0 >> 3, k0 = (uu0 & 7)*64;
    const float* src = w2 + ((size_t)ch*512 + k0)*64;
    #pragma unroll
    for (int j = 0; j < 4; ++j) {
      const int uu = t + j*256;
      const int k = uu >> 4, seg = uu & 15;
      const float4 v = ((const float4*)src)[(size_t)k*16 + seg];
      sm.tile[(seg*4+0)*72 + k] = (_Float16)v.x;
      sm.tile[(seg*4+1)*72 + k] = (_Float16)v.y;
      sm.tile[(seg*4+2)*72 + k] = (_Float16)v.z;
      sm.tile[(seg*4+3)*72 + k] = (_Float16)v.w;
    }
    __syncthreads();
    _Float16* dst = w2T + (size_t)ch*32768;
    #pragma unroll
    for (int j = 0; j < 2; ++j) {
      const int uu = t + j*256;
      const int f = uu >> 3, seg = uu & 7;
      const f16x8 o = *(const f16x8*)&sm.tile[f*72 + seg*8];
      const int kk = k0 + seg*8;
      const int chunk = (f >> 4)*64 + ((seg & 3))*16 + (f & 15);
      *(f16x8*)(dst + (size_t)(kk >> 5)*2048 + chunk*8) = o;
    }
  } else if (u < 1408) {
    const int g = (u - 1152)*4 + w;
    const int base = g*32;
    #pragma unroll
    for (int jb = 0; jb < 4; ++jb) {
      int vals[8];
      #pragma unroll
      for (int i = 0; i < 8; ++i) {
        const int idx = base + jb*8 + i;
        const int b = idx >> 14;
        const int n = (idx >> 4) & (NN - 1);
        const int wd = idx & 15;
        vals[i] = adj[((size_t)b*NN + n)*NN + wd*64 + lane];
      }
      #pragma unroll
      for (int i = 0; i < 8; ++i) {
        const int idx = base + jb*8 + i;
        const int n = (idx >> 4) & (NN - 1);
        const int m = (idx & 15)*64 + lane;
        const unsigned long long bits = __ballot((vals[i] != 0) || (m == n));
        if (lane == 0) bmg[idx] = bits;
      }
    }
  }
}

// ---------------- attn phase (r13 attn_coop body) ----------------
template<int LAYER>
__device__ __forceinline__ void attn_phase(
    int bid, const _Float16* __restrict__ Hp, const float* __restrict__ s_arr,
    const float* __restrict__ d_arr, const unsigned long long* __restrict__ bmg,
    _Float16* __restrict__ outp, SmemU& sm)
{
  const int bch = bid & 31;
  const int r0 = (bid >> 5) * 64;
  const int t = threadIdx.x;
  const int wv = t >> 6, lane = t & 63;
  const int colr = lane & 15, quad = lane >> 4;
  const int b = bch >> 4;

  const float* dg = d_arr + (size_t)bch*NN;
  const float4* dg4 = (const float4*)dg;
  float mxl = -1e30f;
  #pragma unroll
  for (int j = 0; j < 4; ++j) {
    const float4 v = dg4[lane + 64*j];
    mxl = fmaxf(fmaxf(v.x, v.y), fmaxf(fmaxf(v.z, v.w), mxl));
  }
  #pragma unroll
  for (int off = 1; off < 64; off <<= 1) mxl = fmaxf(mxl, __shfl_xor(mxl, off));
  const float maxd = mxl;

  *(float4*)&sm.at.dstg[t*4] = dg4[t];     // stage full d to LDS

  const int r = r0 + wv*16 + colr;
  const float s = s_arr[(size_t)bch*NN + r];
  const float so = s + maxd;
  const float offs = fmaxf(so, 0.2f*so);
  const float sA = s - offs, sB = 0.2f*s - offs;

  unsigned long long m[16];
  {
    const unsigned long long* bm = bmg + ((size_t)b*NN + r)*16;
    #pragma unroll
    for (int j = 0; j < 16; ++j) m[j] = bm[j];
  }

  const _Float16* strip = Hp + (size_t)bch*65536;

  f32x4 acc[4];
  f32x4 accs = {0.f,0.f,0.f,0.f};
  #pragma unroll
  for (int ft = 0; ft < 4; ++ft) acc[ft] = (f32x4){0.f,0.f,0.f,0.f};
  f16x8 ones;
  #pragma unroll
  for (int i = 0; i < 8; ++i) ones[i] = (_Float16)1.f;

  // drain so in-loop vmcnt counts stage ops only; publish dstg
  asm volatile("s_waitcnt vmcnt(0) lgkmcnt(0)" ::: "memory");
  __builtin_amdgcn_s_barrier();

#define STAGE_T(tt) \
    gl_lds16(strip + (size_t)(tt)*2048 + wv*512 + lane*8, &sm.at.stg[(tt) & 1][wv*512]);

  STAGE_T(0);
  asm volatile("s_waitcnt vmcnt(0)" ::: "memory");
  __builtin_amdgcn_s_barrier();

  #pragma unroll 4
  for (int ks = 0; ks < 32; ++ks) {
    if (ks < 31) STAGE_T(ks + 1);          // flies across this step's compute

    f16x8 Bc[4];
    #pragma unroll
    for (int ft = 0; ft < 4; ++ft)
      Bc[ft] = *(const f16x8*)&sm.at.stg[ks & 1][ft*512 + lane*8];
    const float* dls = &sm.at.dstg[ks*32 + quad*8];
    const float4 da0 = *(const float4*)dls;
    const float4 da1 = *(const float4*)(dls + 4);
    asm volatile("s_waitcnt lgkmcnt(0)" ::: "memory");
    __builtin_amdgcn_sched_barrier(0);

    __builtin_amdgcn_s_setprio(1);
    const unsigned mb = (unsigned)((m[ks >> 1] >> ((ks & 1)*32 + quad*8)) & 0xFFull);
    const float dd[8] = {da0.x, da0.y, da0.z, da0.w, da1.x, da1.y, da1.z, da1.w};
    union { f16x8 v; h16x2 hh[4]; } A;
    #pragma unroll
    for (int jp = 0; jp < 4; ++jp) {
      float p[2];
      #pragma unroll
      for (int jj = 0; jj < 2; ++jj) {
        const int j = jp*2 + jj;
        const float dj = dd[j];
        const float l = fmaxf(sA + dj, fmaf(0.2f, dj, sB));  // log2e-scaled domain
        p[jj] = ((mb >> j) & 1u) ? fexp2(l) : 0.f;
      }
      A.hh[jp] = __builtin_amdgcn_cvt_pkrtz(p[0], p[1]);
    }
    #pragma unroll
    for (int ft = 0; ft < 4; ++ft)
      acc[ft] = __builtin_amdgcn_mfma_f32_16x16x32_f16(A.v, Bc[ft], acc[ft], 0, 0, 0);
    accs = __builtin_amdgcn_mfma_f32_16x16x32_f16(A.v, ones, accs, 0, 0, 0);
    __builtin_amdgcn_s_setprio(0);

    if (ks < 31) asm volatile("s_waitcnt vmcnt(0)" ::: "memory");
    __builtin_amdgcn_s_barrier();
  }
#undef STAGE_T

  // epilogue: normalize (LAYER2: /8), per-wave LDS transpose, coalesced f16 writes
  float inv[4];
  #pragma unroll
  for (int i = 0; i < 4; ++i) inv[i] = (LAYER == 2 ? 0.125f : 1.f) / accs[i];
  float (*pw)[68] = sm.at.pw[wv];
  #pragma unroll
  for (int ft = 0; ft < 4; ++ft)
    #pragma unroll
    for (int i = 0; i < 4; ++i)
      pw[quad*4 + i][ft*16 + colr] = acc[ft][i] * inv[i];
  const int row = lane >> 2, f0 = (lane & 3)*16;
  f16x8 o0, o1;
  #pragma unroll
  for (int j = 0; j < 8; ++j) {
    float v0 = pw[row][f0 + j];
    float v1 = pw[row][f0 + 8 + j];
    if (LAYER == 1) {
      v0 = v0 > 0.f ? v0 : expm1f(v0);
      v1 = v1 > 0.f ? v1 : expm1f(v1);
    }
    o0[j] = (_Float16)v0; o1[j] = (_Float16)v1;
  }
  const int rr = r0 + wv*16 + row;
  _Float16* dst;
  if (LAYER == 1) {
    const int bc = bch >> 3, h = bch & 7;
    dst = outp + ((size_t)bc*NN + rr)*512 + h*64 + f0;    // x1 row-major [bc][n][512]
  } else {
    dst = outp + ((size_t)bch*NN + rr)*64 + f0;           // XB [bch][n][64]
  }
  *(f16x8*)dst = o0;
  *(f16x8*)(dst + 8) = o1;
}

// ---------------- proj2 phase (r13 proj2_coop body) ----------------
__device__ __forceinline__ void proj2_phase(
    int bid, const _Float16* __restrict__ x1, const _Float16* __restrict__ w2T,
    const float* __restrict__ asrc2, const float* __restrict__ adst2,
    _Float16* __restrict__ HpT2, float* __restrict__ s2, float* __restrict__ d2,
    SmemU& sm)
{
  const int bch = bid & 31;
  const int r0p = (bid >> 5) * 64;
  const int t = threadIdx.x;
  const int wv = t >> 6, lane = t & 63;
  const int colr = lane & 15, quad = lane >> 4;
  const int h = bch & 7, bc = bch >> 3, c = bc & 1;

  const _Float16* Asrc = x1 + ((size_t)bc*NN + r0p + wv*16 + colr)*512 + quad*8;
  const _Float16* Bsrc = w2T + (size_t)(c*HH + h)*32768 + wv*512 + lane*8;

  f32x4 acc[4];
  #pragma unroll
  for (int ft = 0; ft < 4; ++ft) acc[ft] = (f32x4){0.f,0.f,0.f,0.f};

#define STAGE_P(tt) { \
    gl_lds16(Asrc + (tt)*32,           &sm.p2.Ast[(tt) & 1][wv*512]); \
    gl_lds16(Bsrc + (size_t)(tt)*2048, &sm.p2.Bst[(tt) & 1][wv*512]); }

  STAGE_P(0);
  asm volatile("s_waitcnt vmcnt(0)" ::: "memory");
  __builtin_amdgcn_s_barrier();

  #pragma unroll 4
  for (int ks = 0; ks < 16; ++ks) {
    if (ks < 15) STAGE_P(ks + 1);

    const f16x8 Af = *(const f16x8*)&sm.p2.Ast[ks & 1][wv*512 + lane*8];
    f16x8 Bc[4];
    #pragma unroll
    for (int ft = 0; ft < 4; ++ft)
      Bc[ft] = *(const f16x8*)&sm.p2.Bst[ks & 1][ft*512 + lane*8];
    asm volatile("s_waitcnt lgkmcnt(0)" ::: "memory");
    __builtin_amdgcn_sched_barrier(0);

    __builtin_amdgcn_s_setprio(1);
    #pragma unroll
    for (int ft = 0; ft < 4; ++ft)
      acc[ft] = __builtin_amdgcn_mfma_f32_16x16x32_f16(Af, Bc[ft], acc[ft], 0, 0, 0);
    __builtin_amdgcn_s_setprio(0);

    if (ks < 15) asm volatile("s_waitcnt vmcnt(0)" ::: "memory");
    __builtin_amdgcn_s_barrier();
  }
#undef STAGE_P

  float af[4], bfv[4];
  #pragma unroll
  for (int ft = 0; ft < 4; ++ft) {
    af[ft]  = asrc2[(c*HH + h)*64 + ft*16 + colr];
    bfv[ft] = adst2[(c*HH + h)*64 + ft*16 + colr];
  }
  #pragma unroll
  for (int i = 0; i < 4; ++i) {
    float ps = 0.f, pd = 0.f;
    #pragma unroll
    for (int ft = 0; ft < 4; ++ft) {
      const float v = acc[ft][i];
      const float ex = __expf(2.f*v);
      const float th = 1.f - 2.f/(ex + 1.f);   // tanh(v)
      ps += th * af[ft]; pd += th * bfv[ft];
    }
    #pragma unroll
    for (int off = 1; off < 16; off <<= 1) {
      ps += __shfl_xor(ps, off);
      pd += __shfl_xor(pd, off);
    }
    if (colr == 0) {
      s2[(size_t)bch*NN + r0p + wv*16 + quad*4 + i] = ps * LOG2E;
      d2[(size_t)bch*NN + r0p + wv*16 + quad*4 + i] = pd * LOG2E;
    }
  }
  _Float16* H2 = HpT2 + (size_t)bch*65536 + (size_t)((r0p >> 5) + (wv >> 1))*2048;
  const int cb = (wv & 1)*2 + (quad >> 1);
  #pragma unroll
  for (int ft = 0; ft < 4; ++ft) {
    f16x4 hv;
    #pragma unroll
    for (int i = 0; i < 4; ++i) hv[i] = (_Float16)acc[ft][i];
    const int chunk = ft*64 + cb*16 + colr;
    *(f16x4*)(H2 + chunk*8 + (quad & 1)*4) = hv;
  }
}

// ---------------- Mega-kernel: 5 phases, 4 manual grid barriers ----------------
__global__ __launch_bounds__(256, 2) void gat_mega(
    const float* __restrict__ x, const int* __restrict__ adj,
    const float* __restrict__ w1, const float* __restrict__ as1, const float* __restrict__ ad1,
    const float* __restrict__ w2, const float* __restrict__ as2, const float* __restrict__ ad2,
    _Float16* __restrict__ w2T, unsigned long long* __restrict__ bmg,
    _Float16* __restrict__ HpT, float* __restrict__ s_v, float* __restrict__ d_v,
    _Float16* __restrict__ x1g, _Float16* __restrict__ HpT2,
    float* __restrict__ s2_v, float* __restrict__ d2_v,
    _Float16* __restrict__ XB, float* __restrict__ out,
    unsigned* cnt, unsigned* gen)
{
  __shared__ SmemU sm;
  const int bid = blockIdx.x;

  // P1: striped units {bid, bid+512, bid+1024} — 2 proj + 1 aux per block
  #pragma unroll
  for (int u3 = 0; u3 < 3; ++u3) {
    p1_unit(bid + NBLK*u3, x, adj, w1, w2, as1, ad1, w2T, bmg, HpT, s_v, d_v, sm);
    __syncthreads();
  }
  gbar(cnt, gen, 1u);

  attn_phase<1>(bid, HpT, s_v, d_v, bmg, x1g, sm);
  gbar(cnt, gen, 2u);

  proj2_phase(bid, x1g, w2T, as2, ad2, HpT2, s2_v, d2_v, sm);
  gbar(cnt, gen, 3u);

  attn_phase<2>(bid, HpT2, s2_v, d2_v, bmg, XB, sm);
  gbar(cnt, gen, 4u);

  // reduce: 2 units per block
  #pragma unroll
  for (int j = 0; j < 2; ++j) {
    const int o = (bid + NBLK*j)*256 + (int)threadIdx.x;
    const int f = o & 63;
    const int n = (o >> 6) & (NN - 1);
    const int bc = o >> 16;
    float acc = 0.f;
    #pragma unroll
    for (int h = 0; h < HH; ++h)
      acc += (float)XB[(((size_t)bc*HH + h)*NN + n)*64 + f];
    out[o] = acc;   // 1/8 folded in attn_phase<2>
  }
}

extern "C" void kernel_launch(void* const* d_in, const int* in_sizes, int n_in,
                              void* d_out, int out_size, void* d_ws, size_t ws_size,
                              hipStream_t stream)
{
  const float* x   = (const float*)d_in[0];
  const int*   adj = (const int*)d_in[1];
  const float* w1  = (const float*)d_in[2];
  const float* as1 = (const float*)d_in[3];
  const float* ad1 = (const float*)d_in[4];
  const float* w2  = (const float*)d_in[5];
  const float* as2 = (const float*)d_in[6];
  const float* ad2 = (const float*)d_in[7];

  char* w8 = (char*)d_ws;
  _Float16* HpT  = (_Float16*)(w8);                         // 4 MB  permuted tiles
  _Float16* HpT2 = (_Float16*)(w8 + (4u<<20));              // 4 MB  permuted tiles
  _Float16* w2T  = (_Float16*)(w8 + (8u<<20));              // 1 MB  permuted tiles
  float* s_v  = (float*)(w8 + (10u<<20));                   // 128 KB (log2e-scaled)
  float* d_v  = (float*)(w8 + (10u<<20) + SVN*4);           // 128 KB
  float* s2_v = (float*)(w8 + (10u<<20) + SVN*8);           // 128 KB
  float* d2_v = (float*)(w8 + (10u<<20) + SVN*12);          // 128 KB
  unsigned long long* bmg = (unsigned long long*)(w8 + (10u<<20) + SVN*16);  // 256 KB
  _Float16* x1g = (_Float16*)(w8 + (16u<<20));              // 4 MB  [bc][N][512]
  _Float16* XB  = (_Float16*)(w8 + (20u<<20));              // 4 MB  [bch][N][64]
  unsigned* bar = (unsigned*)(w8 + (24u<<20));              // 16 B barrier state

  hipMemsetAsync(bar, 0, 16, stream);
  gat_mega<<<NBLK, 256, 0, stream>>>(x, adj, w1, as1, ad1, w2, as2, ad2,
                                     w2T, bmg, HpT, s_v, d_v, x1g, HpT2,
                                     s2_v, d2_v, XB, (float*)d_out, bar, bar + 1);
}

// Round 16
// 148.805 us; speedup vs baseline: 2.1490x; 2.1490x over previous
//
#include <hip/hip_runtime.h>

#define BB 2
#define CC 2
#define NN 1024
#define HH 8
#define BCHN 32
#define SVN  (BCHN*NN)       // 32768
#define LOG2E 1.44269504f

typedef _Float16 f16x8 __attribute__((ext_vector_type(8)));
typedef _Float16 f16x4 __attribute__((ext_vector_type(4)));
typedef __fp16 h16x2 __attribute__((ext_vector_type(2)));   // cvt_pkrtz native type
typedef float f32x4 __attribute__((ext_vector_type(4)));

__device__ __forceinline__ float fexp2(float x) {
  float r; asm("v_exp_f32 %0, %1" : "=v"(r) : "v"(x)); return r;
}

// Direct global->LDS staging. LDS dest = wave-uniform base + lane*16B; global src per-lane.
__device__ __forceinline__ void gl_lds16(const _Float16* g, _Float16* l) {
  __builtin_amdgcn_global_load_lds(
      (const __attribute__((address_space(1))) void*)g,
      (__attribute__((address_space(3))) void*)l, 16, 0, 0);
}

// Hp/w2T tiles are 4KB [64 f][32 k] with PERMUTED in-tile order:
//   16B-chunk(f,k) = (f>>4)*64 + ((k>>3)&3)*16 + (f&15), elem j = k&7.
// => MFMA fragment read for (ft, lane) is chunk ft*64 + lane: lane-linear, 0 conflicts.

// ---------------- Fused layer-1 projection + prep (r13, proven) ----------
__global__ __launch_bounds__(256) void proj1_fused(
    const float* __restrict__ x, const int* __restrict__ adj,
    const float* __restrict__ w1, const float* __restrict__ w2,
    const float* __restrict__ asrc, const float* __restrict__ adst,
    _Float16* __restrict__ w2T, unsigned long long* __restrict__ bmg,
    _Float16* __restrict__ HpT, float* __restrict__ s_out, float* __restrict__ d_out)
{
  __shared__ union {
    __align__(16) _Float16 tile[64*72];
    struct { float sp[4][32]; float sd[4][32]; } pr;
  } sm;
  const int bx = blockIdx.x;
  const int t = threadIdx.x;
  const int w = t >> 6, lane = t & 63;
  const int colr = lane & 15, quad = lane >> 4;

  if (bx < 1024) {
    const int bch = bx & 31;
    const int row0 = (bx >> 5) * 32;
    const int h = bch & 7; const int bc = bch >> 3; const int c = bc & 1;

    const float* Ar0 = x + ((size_t)bc*NN + row0 + colr)*64;
    const float* Ar1 = Ar0 + (size_t)16*64;
    const float* Bw  = w1 + ((size_t)(c*HH + h))*64*64 + w*16 + colr;

    f32x4 acc0 = {0.f,0.f,0.f,0.f}, acc1 = {0.f,0.f,0.f,0.f};
    #pragma unroll
    for (int kb = 0; kb < 64; kb += 32) {
      const float4 pa0 = *(const float4*)(Ar0 + kb + quad*8);
      const float4 pa1 = *(const float4*)(Ar0 + kb + quad*8 + 4);
      const float4 pb0 = *(const float4*)(Ar1 + kb + quad*8);
      const float4 pb1 = *(const float4*)(Ar1 + kb + quad*8 + 4);
      float bv[8];
      #pragma unroll
      for (int j = 0; j < 8; ++j) bv[j] = Bw[(size_t)(kb + quad*8 + j)*64];
      f16x8 a0, a1, bf;
      a0[0]=(_Float16)pa0.x; a0[1]=(_Float16)pa0.y; a0[2]=(_Float16)pa0.z; a0[3]=(_Float16)pa0.w;
      a0[4]=(_Float16)pa1.x; a0[5]=(_Float16)pa1.y; a0[6]=(_Float16)pa1.z; a0[7]=(_Float16)pa1.w;
      a1[0]=(_Float16)pb0.x; a1[1]=(_Float16)pb0.y; a1[2]=(_Float16)pb0.z; a1[3]=(_Float16)pb0.w;
      a1[4]=(_Float16)pb1.x; a1[5]=(_Float16)pb1.y; a1[6]=(_Float16)pb1.z; a1[7]=(_Float16)pb1.w;
      #pragma unroll
      for (int j = 0; j < 8; ++j) bf[j] = (_Float16)bv[j];
      acc0 = __builtin_amdgcn_mfma_f32_16x16x32_f16(a0, bf, acc0, 0, 0, 0);
      acc1 = __builtin_amdgcn_mfma_f32_16x16x32_f16(a1, bf, acc1, 0, 0, 0);
    }

    const float af  = asrc[(c*HH + h)*64 + w*16 + colr];
    const float bf_ = adst[(c*HH + h)*64 + w*16 + colr];
    _Float16* HT = HpT + (size_t)bch*65536 + (size_t)(row0 >> 5)*2048;

    #pragma unroll
    for (int mt = 0; mt < 2; ++mt) {
      const f32x4 a = mt ? acc1 : acc0;
      f16x4 hv;
      #pragma unroll
      for (int i = 0; i < 4; ++i) {
        const float v = a[i];
        hv[i] = (_Float16)v;
        const float ex = __expf(2.f*v);
        const float th = 1.f - 2.f/(ex + 1.f);         // tanh(v)
        float ps = th * af, pd = th * bf_;
        #pragma unroll
        for (int off = 1; off < 16; off <<= 1) {
          ps += __shfl_xor(ps, off);
          pd += __shfl_xor(pd, off);
        }
        if (colr == 0) {
          sm.pr.sp[w][mt*16 + quad*4 + i] = ps;
          sm.pr.sd[w][mt*16 + quad*4 + i] = pd;
        }
      }
      const int chunk = w*64 + (mt*2 + (quad >> 1))*16 + colr;
      *(f16x4*)(HT + chunk*8 + (quad & 1)*4) = hv;
    }
    __syncthreads();
    if (t < 32) {
      const float sv = sm.pr.sp[0][t] + sm.pr.sp[1][t] + sm.pr.sp[2][t] + sm.pr.sp[3][t];
      const float dv = sm.pr.sd[0][t] + sm.pr.sd[1][t] + sm.pr.sd[2][t] + sm.pr.sd[3][t];
      s_out[bch*NN + row0 + t] = sv * LOG2E;
      d_out[bch*NN + row0 + t] = dv * LOG2E;
    }
  } else if (bx < 1152) {
    const int u = bx - 1024;
    const int ch = u >> 3, k0 = (u & 7)*64;
    const float* src = w2 + ((size_t)ch*512 + k0)*64;
    #pragma unroll
    for (int j = 0; j < 4; ++j) {
      const int uu = t + j*256;
      const int k = uu >> 4, seg = uu & 15;
      const float4 v = ((const float4*)src)[(size_t)k*16 + seg];
      sm.tile[(seg*4+0)*72 + k] = (_Float16)v.x;
      sm.tile[(seg*4+1)*72 + k] = (_Float16)v.y;
      sm.tile[(seg*4+2)*72 + k] = (_Float16)v.z;
      sm.tile[(seg*4+3)*72 + k] = (_Float16)v.w;
    }
    __syncthreads();
    _Float16* dst = w2T + (size_t)ch*32768;
    #pragma unroll
    for (int j = 0; j < 2; ++j) {
      const int uu = t + j*256;
      const int f = uu >> 3, seg = uu & 7;
      const f16x8 o = *(const f16x8*)&sm.tile[f*72 + seg*8];
      const int kk = k0 + seg*8;
      const int chunk = (f >> 4)*64 + ((seg & 3))*16 + (f & 15);
      *(f16x8*)(dst + (size_t)(kk >> 5)*2048 + chunk*8) = o;
    }
  } else {
    const int g = (bx - 1152)*4 + w;
    const int base = g*32;
    #pragma unroll
    for (int jb = 0; jb < 4; ++jb) {
      int vals[8];
      #pragma unroll
      for (int i = 0; i < 8; ++i) {
        const int idx = base + jb*8 + i;
        const int b = idx >> 14;
        const int n = (idx >> 4) & (NN - 1);
        const int wd = idx & 15;
        vals[i] = adj[((size_t)b*NN + n)*NN + wd*64 + lane];
      }
      #pragma unroll
      for (int i = 0; i < 8; ++i) {
        const int idx = base + jb*8 + i;
        const int n = (idx >> 4) & (NN - 1);
        const int m = (idx & 15)*64 + lane;
        const unsigned long long bits = __ballot((vals[i] != 0) || (m == n));
        if (lane == 0) bmg[idx] = bits;
      }
    }
  }
}

// ---------------- attn_coop<LAYER>: 64 rows/block, block-cooperative B staging ----------
// LAYER 1: x1 = elu(O/dsum) -> x1g [bc][n][512] (LDS transpose epilogue).
// LAYER 2: O/(8*dsum) atomically accumulated into f32 out (reduce fused; out pre-zeroed).
template<int LAYER>
__global__ __launch_bounds__(256) void attn_coop(
    const _Float16* __restrict__ Hp, const float* __restrict__ s_arr,
    const float* __restrict__ d_arr, const unsigned long long* __restrict__ bmg,
    _Float16* __restrict__ outp, float* __restrict__ outf)
{
  __shared__ struct {
    __align__(16) _Float16 stg[2][2048];   // 8 KB: 2 slots of one 4KB tile
    __align__(16) float dstg[1024];        // 4 KB full d[bch]
    float pw[4][16][68];                   // 17.4 KB epilogue transpose (LAYER 1)
  } sm;
  const int bch = blockIdx.x;
  const int r0 = blockIdx.y * 64;
  const int t = threadIdx.x;
  const int wv = t >> 6, lane = t & 63;
  const int colr = lane & 15, quad = lane >> 4;
  const int b = bch >> 4;

  // maxd over full d[bch]
  const float* dg = d_arr + (size_t)bch*NN;
  const float4* dg4 = (const float4*)dg;
  float mxl = -1e30f;
  #pragma unroll
  for (int j = 0; j < 4; ++j) {
    const float4 v = dg4[lane + 64*j];
    mxl = fmaxf(fmaxf(v.x, v.y), fmaxf(fmaxf(v.z, v.w), mxl));
  }
  #pragma unroll
  for (int off = 1; off < 64; off <<= 1) mxl = fmaxf(mxl, __shfl_xor(mxl, off));
  const float maxd = mxl;

  *(float4*)&sm.dstg[t*4] = dg4[t];        // stage full d to LDS

  const int r = r0 + wv*16 + colr;
  const float s = s_arr[(size_t)bch*NN + r];
  const float so = s + maxd;
  const float offs = fmaxf(so, 0.2f*so);
  const float sA = s - offs, sB = 0.2f*s - offs;

  unsigned long long m[16];
  {
    const unsigned long long* bm = bmg + ((size_t)b*NN + r)*16;
    #pragma unroll
    for (int j = 0; j < 16; ++j) m[j] = bm[j];
  }

  const _Float16* strip = Hp + (size_t)bch*65536;

  f32x4 acc[4];
  f32x4 accs = {0.f,0.f,0.f,0.f};
  #pragma unroll
  for (int ft = 0; ft < 4; ++ft) acc[ft] = (f32x4){0.f,0.f,0.f,0.f};
  f16x8 ones;
  #pragma unroll
  for (int i = 0; i < 8; ++i) ones[i] = (_Float16)1.f;

  // drain prologue VMEM so in-loop vmcnt counts stage ops only; publish dstg
  asm volatile("s_waitcnt vmcnt(0) lgkmcnt(0)" ::: "memory");
  __builtin_amdgcn_s_barrier();

#define STAGE_T(tt) \
    gl_lds16(strip + (size_t)(tt)*2048 + wv*512 + lane*8, &sm.stg[(tt) & 1][wv*512]);

  STAGE_T(0);
  asm volatile("s_waitcnt vmcnt(0)" ::: "memory");
  __builtin_amdgcn_s_barrier();

  #pragma unroll 4
  for (int ks = 0; ks < 32; ++ks) {
    if (ks < 31) STAGE_T(ks + 1);          // flies across this step's compute

    f16x8 Bc[4];
    #pragma unroll
    for (int ft = 0; ft < 4; ++ft)
      Bc[ft] = *(const f16x8*)&sm.stg[ks & 1][ft*512 + lane*8];
    const float* dls = &sm.dstg[ks*32 + quad*8];
    const float4 da0 = *(const float4*)dls;
    const float4 da1 = *(const float4*)(dls + 4);
    asm volatile("s_waitcnt lgkmcnt(0)" ::: "memory");
    __builtin_amdgcn_sched_barrier(0);

    __builtin_amdgcn_s_setprio(1);
    const unsigned mb = (unsigned)((m[ks >> 1] >> ((ks & 1)*32 + quad*8)) & 0xFFull);
    const float dd[8] = {da0.x, da0.y, da0.z, da0.w, da1.x, da1.y, da1.z, da1.w};
    union { f16x8 v; h16x2 hh[4]; } A;
    #pragma unroll
    for (int jp = 0; jp < 4; ++jp) {
      float p[2];
      #pragma unroll
      for (int jj = 0; jj < 2; ++jj) {
        const int j = jp*2 + jj;
        const float dj = dd[j];
        const float l = fmaxf(sA + dj, fmaf(0.2f, dj, sB));  // log2e-scaled domain
        p[jj] = ((mb >> j) & 1u) ? fexp2(l) : 0.f;
      }
      A.hh[jp] = __builtin_amdgcn_cvt_pkrtz(p[0], p[1]);
    }
    #pragma unroll
    for (int ft = 0; ft < 4; ++ft)
      acc[ft] = __builtin_amdgcn_mfma_f32_16x16x32_f16(A.v, Bc[ft], acc[ft], 0, 0, 0);
    accs = __builtin_amdgcn_mfma_f32_16x16x32_f16(A.v, ones, accs, 0, 0, 0);
    __builtin_amdgcn_s_setprio(0);

    if (ks < 31) asm volatile("s_waitcnt vmcnt(0)" ::: "memory");
    __builtin_amdgcn_s_barrier();
  }
#undef STAGE_T

  if (LAYER == 2) {
    // fused reduce: atomically accumulate O/(8*dsum) into f32 out (pre-zeroed).
    // acc[ft][i] = O[row=r0+wv*16+quad*4+i][f=ft*16+colr] (mapping verified by r13 pass)
    const int bc = bch >> 3;
    float inv[4];
    #pragma unroll
    for (int i = 0; i < 4; ++i) inv[i] = 0.125f / accs[i];
    float* ob = outf + ((size_t)bc*NN + r0 + wv*16)*64;
    #pragma unroll
    for (int ft = 0; ft < 4; ++ft)
      #pragma unroll
      for (int i = 0; i < 4; ++i)
        atomicAdd(ob + (size_t)(quad*4 + i)*64 + ft*16 + colr, acc[ft][i] * inv[i]);
    return;
  }

  // LAYER 1 epilogue: normalize, per-wave LDS transpose, elu, coalesced f16 writes
  float inv[4];
  #pragma unroll
  for (int i = 0; i < 4; ++i) inv[i] = 1.f / accs[i];
  float (*pw)[68] = sm.pw[wv];
  #pragma unroll
  for (int ft = 0; ft < 4; ++ft)
    #pragma unroll
    for (int i = 0; i < 4; ++i)
      pw[quad*4 + i][ft*16 + colr] = acc[ft][i] * inv[i];
  const int row = lane >> 2, f0 = (lane & 3)*16;
  f16x8 o0, o1;
  #pragma unroll
  for (int j = 0; j < 8; ++j) {
    float v0 = pw[row][f0 + j];
    float v1 = pw[row][f0 + 8 + j];
    v0 = v0 > 0.f ? v0 : expm1f(v0);
    v1 = v1 > 0.f ? v1 : expm1f(v1);
    o0[j] = (_Float16)v0; o1[j] = (_Float16)v1;
  }
  const int rr = r0 + wv*16 + row;
  const int bc = bch >> 3, h = bch & 7;
  _Float16* dst = outp + ((size_t)bc*NN + rr)*512 + h*64 + f0;   // x1 [bc][n][512]
  *(f16x8*)dst = o0;
  *(f16x8*)(dst + 8) = o1;
}

// ---------------- proj2_coop (r13, proven) ----------
__global__ __launch_bounds__(256) void proj2_coop(
    const _Float16* __restrict__ x1, const _Float16* __restrict__ w2T,
    const float* __restrict__ asrc2, const float* __restrict__ adst2,
    _Float16* __restrict__ HpT2, float* __restrict__ s2, float* __restrict__ d2)
{
  __shared__ struct {
    __align__(16) _Float16 Ast[2][2048];   // 8 KB
    __align__(16) _Float16 Bst[2][2048];   // 8 KB
  } sm;
  const int bch = blockIdx.x;
  const int r0p = blockIdx.y * 64;
  const int t = threadIdx.x;
  const int wv = t >> 6, lane = t & 63;
  const int colr = lane & 15, quad = lane >> 4;
  const int h = bch & 7, bc = bch >> 3, c = bc & 1;

  const _Float16* Asrc = x1 + ((size_t)bc*NN + r0p + wv*16 + colr)*512 + quad*8;
  const _Float16* Bsrc = w2T + (size_t)(c*HH + h)*32768 + wv*512 + lane*8;

  f32x4 acc[4];
  #pragma unroll
  for (int ft = 0; ft < 4; ++ft) acc[ft] = (f32x4){0.f,0.f,0.f,0.f};

#define STAGE_P(tt) { \
    gl_lds16(Asrc + (tt)*32,           &sm.Ast[(tt) & 1][wv*512]); \
    gl_lds16(Bsrc + (size_t)(tt)*2048, &sm.Bst[(tt) & 1][wv*512]); }

  STAGE_P(0);
  asm volatile("s_waitcnt vmcnt(0)" ::: "memory");
  __builtin_amdgcn_s_barrier();

  #pragma unroll 4
  for (int ks = 0; ks < 16; ++ks) {
    if (ks < 15) STAGE_P(ks + 1);

    const f16x8 Af = *(const f16x8*)&sm.Ast[ks & 1][wv*512 + lane*8];
    f16x8 Bc[4];
    #pragma unroll
    for (int ft = 0; ft < 4; ++ft)
      Bc[ft] = *(const f16x8*)&sm.Bst[ks & 1][ft*512 + lane*8];
    asm volatile("s_waitcnt lgkmcnt(0)" ::: "memory");
    __builtin_amdgcn_sched_barrier(0);

    __builtin_amdgcn_s_setprio(1);
    #pragma unroll
    for (int ft = 0; ft < 4; ++ft)
      acc[ft] = __builtin_amdgcn_mfma_f32_16x16x32_f16(Af, Bc[ft], acc[ft], 0, 0, 0);
    __builtin_amdgcn_s_setprio(0);

    if (ks < 15) asm volatile("s_waitcnt vmcnt(0)" ::: "memory");
    __builtin_amdgcn_s_barrier();
  }
#undef STAGE_P

  float af[4], bfv[4];
  #pragma unroll
  for (int ft = 0; ft < 4; ++ft) {
    af[ft]  = asrc2[(c*HH + h)*64 + ft*16 + colr];
    bfv[ft] = adst2[(c*HH + h)*64 + ft*16 + colr];
  }
  #pragma unroll
  for (int i = 0; i < 4; ++i) {
    float ps = 0.f, pd = 0.f;
    #pragma unroll
    for (int ft = 0; ft < 4; ++ft) {
      const float v = acc[ft][i];
      const float ex = __expf(2.f*v);
      const float th = 1.f - 2.f/(ex + 1.f);   // tanh(v)
      ps += th * af[ft]; pd += th * bfv[ft];
    }
    #pragma unroll
    for (int off = 1; off < 16; off <<= 1) {
      ps += __shfl_xor(ps, off);
      pd += __shfl_xor(pd, off);
    }
    if (colr == 0) {
      s2[(size_t)bch*NN + r0p + wv*16 + quad*4 + i] = ps * LOG2E;
      d2[(size_t)bch*NN + r0p + wv*16 + quad*4 + i] = pd * LOG2E;
    }
  }
  _Float16* H2 = HpT2 + (size_t)bch*65536 + (size_t)((r0p >> 5) + (wv >> 1))*2048;
  const int cb = (wv & 1)*2 + (quad >> 1);
  #pragma unroll
  for (int ft = 0; ft < 4; ++ft) {
    f16x4 hv;
    #pragma unroll
    for (int i = 0; i < 4; ++i) hv[i] = (_Float16)acc[ft][i];
    const int chunk = ft*64 + cb*16 + colr;
    *(f16x4*)(H2 + chunk*8 + (quad & 1)*4) = hv;
  }
}

extern "C" void kernel_launch(void* const* d_in, const int* in_sizes, int n_in,
                              void* d_out, int out_size, void* d_ws, size_t ws_size,
                              hipStream_t stream)
{
  const float* x   = (const float*)d_in[0];
  const int*   adj = (const int*)d_in[1];
  const float* w1  = (const float*)d_in[2];
  const float* as1 = (const float*)d_in[3];
  const float* ad1 = (const float*)d_in[4];
  const float* w2  = (const float*)d_in[5];
  const float* as2 = (const float*)d_in[6];
  const float* ad2 = (const float*)d_in[7];

  char* w8 = (char*)d_ws;
  _Float16* HpT  = (_Float16*)(w8);                         // 4 MB  permuted tiles
  _Float16* HpT2 = (_Float16*)(w8 + (4u<<20));              // 4 MB  permuted tiles
  _Float16* w2T  = (_Float16*)(w8 + (8u<<20));              // 1 MB  permuted tiles
  float* s_v  = (float*)(w8 + (10u<<20));                   // 128 KB (log2e-scaled)
  float* d_v  = (float*)(w8 + (10u<<20) + SVN*4);           // 128 KB
  float* s2_v = (float*)(w8 + (10u<<20) + SVN*8);           // 128 KB
  float* d2_v = (float*)(w8 + (10u<<20) + SVN*12);          // 128 KB
  unsigned long long* bmg = (unsigned long long*)(w8 + (10u<<20) + SVN*16);  // 256 KB
  _Float16* x1g = (_Float16*)(w8 + (16u<<20));              // 4 MB  [bc][N][512]

  // zero output: attn2 accumulates heads via atomics (graph-safe async memset)
  hipMemsetAsync(d_out, 0, (size_t)out_size * sizeof(float), stream);

  proj1_fused<<<1408, 256, 0, stream>>>(x, adj, w1, w2, as1, ad1, w2T, bmg, HpT, s_v, d_v);
  attn_coop<1><<<dim3(BCHN, NN/64), 256, 0, stream>>>(HpT, s_v, d_v, bmg, x1g, nullptr);
  proj2_coop<<<dim3(BCHN, NN/64), 256, 0, stream>>>(x1g, w2T, as2, ad2, HpT2, s2_v, d2_v);
  attn_coop<2><<<dim3(BCHN, NN/64), 256, 0, stream>>>(HpT2, s2_v, d2_v, bmg, nullptr,
                                                      (float*)d_out);
}

// Round 17
// 142.905 us; speedup vs baseline: 2.2377x; 1.0413x over previous
//
#include <hip/hip_runtime.h>

#define BB 2
#define CC 2
#define NN 1024
#define HH 8
#define BCHN 32
#define SVN  (BCHN*NN)       // 32768
#define LOG2E 1.44269504f

typedef _Float16 f16x8 __attribute__((ext_vector_type(8)));
typedef _Float16 f16x4 __attribute__((ext_vector_type(4)));
typedef __fp16 h16x2 __attribute__((ext_vector_type(2)));   // cvt_pkrtz native type
typedef float f32x4 __attribute__((ext_vector_type(4)));

__device__ __forceinline__ float fexp2(float x) {
  float r; asm("v_exp_f32 %0, %1" : "=v"(r) : "v"(x)); return r;
}

// Direct global->LDS staging. LDS dest = wave-uniform base + lane*16B; global src per-lane.
__device__ __forceinline__ void gl_lds16(const _Float16* g, _Float16* l) {
  __builtin_amdgcn_global_load_lds(
      (const __attribute__((address_space(1))) void*)g,
      (__attribute__((address_space(3))) void*)l, 16, 0, 0);
}

// Hp/w2T tiles are 4KB [64 f][32 k] with PERMUTED in-tile order:
//   16B-chunk(f,k) = (f>>4)*64 + ((k>>3)&3)*16 + (f&15), elem j = k&7.
// => MFMA fragment read for (ft, lane) is chunk ft*64 + lane: lane-linear, 0 conflicts.

// ---------------- Fused layer-1 projection + prep (r13, proven) ----------
__global__ __launch_bounds__(256) void proj1_fused(
    const float* __restrict__ x, const int* __restrict__ adj,
    const float* __restrict__ w1, const float* __restrict__ w2,
    const float* __restrict__ asrc, const float* __restrict__ adst,
    _Float16* __restrict__ w2T, unsigned long long* __restrict__ bmg,
    _Float16* __restrict__ HpT, float* __restrict__ s_out, float* __restrict__ d_out)
{
  __shared__ union {
    __align__(16) _Float16 tile[64*72];
    struct { float sp[4][32]; float sd[4][32]; } pr;
  } sm;
  const int bx = blockIdx.x;
  const int t = threadIdx.x;
  const int w = t >> 6, lane = t & 63;
  const int colr = lane & 15, quad = lane >> 4;

  if (bx < 1024) {
    const int bch = bx & 31;
    const int row0 = (bx >> 5) * 32;
    const int h = bch & 7; const int bc = bch >> 3; const int c = bc & 1;

    const float* Ar0 = x + ((size_t)bc*NN + row0 + colr)*64;
    const float* Ar1 = Ar0 + (size_t)16*64;
    const float* Bw  = w1 + ((size_t)(c*HH + h))*64*64 + w*16 + colr;

    f32x4 acc0 = {0.f,0.f,0.f,0.f}, acc1 = {0.f,0.f,0.f,0.f};
    #pragma unroll
    for (int kb = 0; kb < 64; kb += 32) {
      const float4 pa0 = *(const float4*)(Ar0 + kb + quad*8);
      const float4 pa1 = *(const float4*)(Ar0 + kb + quad*8 + 4);
      const float4 pb0 = *(const float4*)(Ar1 + kb + quad*8);
      const float4 pb1 = *(const float4*)(Ar1 + kb + quad*8 + 4);
      float bv[8];
      #pragma unroll
      for (int j = 0; j < 8; ++j) bv[j] = Bw[(size_t)(kb + quad*8 + j)*64];
      f16x8 a0, a1, bf;
      a0[0]=(_Float16)pa0.x; a0[1]=(_Float16)pa0.y; a0[2]=(_Float16)pa0.z; a0[3]=(_Float16)pa0.w;
      a0[4]=(_Float16)pa1.x; a0[5]=(_Float16)pa1.y; a0[6]=(_Float16)pa1.z; a0[7]=(_Float16)pa1.w;
      a1[0]=(_Float16)pb0.x; a1[1]=(_Float16)pb0.y; a1[2]=(_Float16)pb0.z; a1[3]=(_Float16)pb0.w;
      a1[4]=(_Float16)pb1.x; a1[5]=(_Float16)pb1.y; a1[6]=(_Float16)pb1.z; a1[7]=(_Float16)pb1.w;
      #pragma unroll
      for (int j = 0; j < 8; ++j) bf[j] = (_Float16)bv[j];
      acc0 = __builtin_amdgcn_mfma_f32_16x16x32_f16(a0, bf, acc0, 0, 0, 0);
      acc1 = __builtin_amdgcn_mfma_f32_16x16x32_f16(a1, bf, acc1, 0, 0, 0);
    }

    const float af  = asrc[(c*HH + h)*64 + w*16 + colr];
    const float bf_ = adst[(c*HH + h)*64 + w*16 + colr];
    _Float16* HT = HpT + (size_t)bch*65536 + (size_t)(row0 >> 5)*2048;

    #pragma unroll
    for (int mt = 0; mt < 2; ++mt) {
      const f32x4 a = mt ? acc1 : acc0;
      f16x4 hv;
      #pragma unroll
      for (int i = 0; i < 4; ++i) {
        const float v = a[i];
        hv[i] = (_Float16)v;
        const float ex = __expf(2.f*v);
        const float th = 1.f - 2.f/(ex + 1.f);         // tanh(v)
        float ps = th * af, pd = th * bf_;
        #pragma unroll
        for (int off = 1; off < 16; off <<= 1) {
          ps += __shfl_xor(ps, off);
          pd += __shfl_xor(pd, off);
        }
        if (colr == 0) {
          sm.pr.sp[w][mt*16 + quad*4 + i] = ps;
          sm.pr.sd[w][mt*16 + quad*4 + i] = pd;
        }
      }
      const int chunk = w*64 + (mt*2 + (quad >> 1))*16 + colr;
      *(f16x4*)(HT + chunk*8 + (quad & 1)*4) = hv;
    }
    __syncthreads();
    if (t < 32) {
      const float sv = sm.pr.sp[0][t] + sm.pr.sp[1][t] + sm.pr.sp[2][t] + sm.pr.sp[3][t];
      const float dv = sm.pr.sd[0][t] + sm.pr.sd[1][t] + sm.pr.sd[2][t] + sm.pr.sd[3][t];
      s_out[bch*NN + row0 + t] = sv * LOG2E;
      d_out[bch*NN + row0 + t] = dv * LOG2E;
    }
  } else if (bx < 1152) {
    const int u = bx - 1024;
    const int ch = u >> 3, k0 = (u & 7)*64;
    const float* src = w2 + ((size_t)ch*512 + k0)*64;
    #pragma unroll
    for (int j = 0; j < 4; ++j) {
      const int uu = t + j*256;
      const int k = uu >> 4, seg = uu & 15;
      const float4 v = ((const float4*)src)[(size_t)k*16 + seg];
      sm.tile[(seg*4+0)*72 + k] = (_Float16)v.x;
      sm.tile[(seg*4+1)*72 + k] = (_Float16)v.y;
      sm.tile[(seg*4+2)*72 + k] = (_Float16)v.z;
      sm.tile[(seg*4+3)*72 + k] = (_Float16)v.w;
    }
    __syncthreads();
    _Float16* dst = w2T + (size_t)ch*32768;
    #pragma unroll
    for (int j = 0; j < 2; ++j) {
      const int uu = t + j*256;
      const int f = uu >> 3, seg = uu & 7;
      const f16x8 o = *(const f16x8*)&sm.tile[f*72 + seg*8];
      const int kk = k0 + seg*8;
      const int chunk = (f >> 4)*64 + ((seg & 3))*16 + (f & 15);
      *(f16x8*)(dst + (size_t)(kk >> 5)*2048 + chunk*8) = o;
    }
  } else {
    const int g = (bx - 1152)*4 + w;
    const int base = g*32;
    #pragma unroll
    for (int jb = 0; jb < 4; ++jb) {
      int vals[8];
      #pragma unroll
      for (int i = 0; i < 8; ++i) {
        const int idx = base + jb*8 + i;
        const int b = idx >> 14;
        const int n = (idx >> 4) & (NN - 1);
        const int wd = idx & 15;
        vals[i] = adj[((size_t)b*NN + n)*NN + wd*64 + lane];
      }
      #pragma unroll
      for (int i = 0; i < 8; ++i) {
        const int idx = base + jb*8 + i;
        const int n = (idx >> 4) & (NN - 1);
        const int m = (idx & 15)*64 + lane;
        const unsigned long long bits = __ballot((vals[i] != 0) || (m == n));
        if (lane == 0) bmg[idx] = bits;
      }
    }
  }
}

// ---------------- attn_coop<LAYER>: coop B staging, 3-slot depth-2, FULL unroll ----------
// grid (bch=32, rt=16) = 512 blocks; 4 waves share one k-walk.
// vmcnt(1) before barrier => stage(ks) landed, stage(ks+1) still in flight (never drain 0
// mid-loop). stage(ks+2) issued after barrier (its slot's readers finished pre-barrier).
template<int LAYER>
__global__ __launch_bounds__(256) void attn_coop(
    const _Float16* __restrict__ Hp, const float* __restrict__ s_arr,
    const float* __restrict__ d_arr, const unsigned long long* __restrict__ bmg,
    _Float16* __restrict__ outp)
{
  __shared__ struct {
    __align__(16) _Float16 stg[3][2048];   // 12 KB: 3 slots (depth-2)
    __align__(16) float dstg[1024];        // 4 KB full d[bch]
    float pw[4][16][68];                   // 17.4 KB epilogue transpose
  } sm;
  const int bch = blockIdx.x;
  const int r0 = blockIdx.y * 64;
  const int t = threadIdx.x;
  const int wv = t >> 6, lane = t & 63;
  const int colr = lane & 15, quad = lane >> 4;
  const int b = bch >> 4;

  // maxd over full d[bch]
  const float* dg = d_arr + (size_t)bch*NN;
  const float4* dg4 = (const float4*)dg;
  float mxl = -1e30f;
  #pragma unroll
  for (int j = 0; j < 4; ++j) {
    const float4 v = dg4[lane + 64*j];
    mxl = fmaxf(fmaxf(v.x, v.y), fmaxf(fmaxf(v.z, v.w), mxl));
  }
  #pragma unroll
  for (int off = 1; off < 64; off <<= 1) mxl = fmaxf(mxl, __shfl_xor(mxl, off));
  const float maxd = mxl;

  *(float4*)&sm.dstg[t*4] = dg4[t];        // stage full d to LDS

  const int r = r0 + wv*16 + colr;
  const float s = s_arr[(size_t)bch*NN + r];
  const float so = s + maxd;
  const float offs = fmaxf(so, 0.2f*so);
  const float sA = s - offs, sB = 0.2f*s - offs;

  unsigned long long m[16];
  {
    const unsigned long long* bm = bmg + ((size_t)b*NN + r)*16;
    #pragma unroll
    for (int j = 0; j < 16; ++j) m[j] = bm[j];
  }

  const _Float16* strip = Hp + (size_t)bch*65536;

  f32x4 acc[4];
  f32x4 accs = {0.f,0.f,0.f,0.f};
  #pragma unroll
  for (int ft = 0; ft < 4; ++ft) acc[ft] = (f32x4){0.f,0.f,0.f,0.f};
  f16x8 ones;
  #pragma unroll
  for (int i = 0; i < 8; ++i) ones[i] = (_Float16)1.f;

  // drain prologue VMEM (exact in-loop vmcnt counting) + publish dstg
  asm volatile("s_waitcnt vmcnt(0) lgkmcnt(0)" ::: "memory");
  __builtin_amdgcn_s_barrier();

#define STAGE_T(tt, slot) \
    gl_lds16(strip + (size_t)(tt)*2048 + wv*512 + lane*8, &sm.stg[slot][wv*512]);

  STAGE_T(0, 0);
  STAGE_T(1, 1);

  #pragma unroll
  for (int ks = 0; ks < 32; ++ks) {
    if (ks < 31) asm volatile("s_waitcnt vmcnt(1)" ::: "memory");
    else         asm volatile("s_waitcnt vmcnt(0)" ::: "memory");
    __builtin_amdgcn_s_barrier();          // all waves' stage(ks) visible; prior reads done
    if (ks < 30) STAGE_T(ks + 2, (ks + 2) % 3);

    f16x8 Bc[4];
    #pragma unroll
    for (int ft = 0; ft < 4; ++ft)
      Bc[ft] = *(const f16x8*)&sm.stg[ks % 3][ft*512 + lane*8];
    const float* dls = &sm.dstg[ks*32 + quad*8];
    const float4 da0 = *(const float4*)dls;
    const float4 da1 = *(const float4*)(dls + 4);
    asm volatile("s_waitcnt lgkmcnt(0)" ::: "memory");
    __builtin_amdgcn_sched_barrier(0);

    __builtin_amdgcn_s_setprio(1);
    const unsigned mb = (unsigned)((m[ks >> 1] >> ((ks & 1)*32 + quad*8)) & 0xFFull);
    const float dd[8] = {da0.x, da0.y, da0.z, da0.w, da1.x, da1.y, da1.z, da1.w};
    union { f16x8 v; h16x2 hh[4]; } A;
    #pragma unroll
    for (int jp = 0; jp < 4; ++jp) {
      float p[2];
      #pragma unroll
      for (int jj = 0; jj < 2; ++jj) {
        const int j = jp*2 + jj;
        const float dj = dd[j];
        const float l = fmaxf(sA + dj, fmaf(0.2f, dj, sB));  // log2e-scaled domain
        p[jj] = ((mb >> j) & 1u) ? fexp2(l) : 0.f;
      }
      A.hh[jp] = __builtin_amdgcn_cvt_pkrtz(p[0], p[1]);
    }
    #pragma unroll
    for (int ft = 0; ft < 4; ++ft)
      acc[ft] = __builtin_amdgcn_mfma_f32_16x16x32_f16(A.v, Bc[ft], acc[ft], 0, 0, 0);
    accs = __builtin_amdgcn_mfma_f32_16x16x32_f16(A.v, ones, accs, 0, 0, 0);
    __builtin_amdgcn_s_setprio(0);
  }
#undef STAGE_T

  // epilogue: normalize (LAYER2: /8), per-wave LDS transpose, coalesced f16 writes
  float inv[4];
  #pragma unroll
  for (int i = 0; i < 4; ++i) inv[i] = (LAYER == 2 ? 0.125f : 1.f) / accs[i];
  float (*pw)[68] = sm.pw[wv];
  #pragma unroll
  for (int ft = 0; ft < 4; ++ft)
    #pragma unroll
    for (int i = 0; i < 4; ++i)
      pw[quad*4 + i][ft*16 + colr] = acc[ft][i] * inv[i];
  const int row = lane >> 2, f0 = (lane & 3)*16;
  f16x8 o0, o1;
  #pragma unroll
  for (int j = 0; j < 8; ++j) {
    float v0 = pw[row][f0 + j];
    float v1 = pw[row][f0 + 8 + j];
    if (LAYER == 1) {
      v0 = v0 > 0.f ? v0 : expm1f(v0);
      v1 = v1 > 0.f ? v1 : expm1f(v1);
    }
    o0[j] = (_Float16)v0; o1[j] = (_Float16)v1;
  }
  const int rr = r0 + wv*16 + row;
  _Float16* dst;
  if (LAYER == 1) {
    const int bc = bch >> 3, h = bch & 7;
    dst = outp + ((size_t)bc*NN + rr)*512 + h*64 + f0;    // x1 row-major [bc][n][512]
  } else {
    dst = outp + ((size_t)bch*NN + rr)*64 + f0;           // XB [bch][n][64]
  }
  *(f16x8*)dst = o0;
  *(f16x8*)(dst + 8) = o1;
}

// ---------------- proj2_coop: coop A+B staging, 3-slot depth-2, FULL unroll ----------
__global__ __launch_bounds__(256) void proj2_coop(
    const _Float16* __restrict__ x1, const _Float16* __restrict__ w2T,
    const float* __restrict__ asrc2, const float* __restrict__ adst2,
    _Float16* __restrict__ HpT2, float* __restrict__ s2, float* __restrict__ d2)
{
  __shared__ struct {
    __align__(16) _Float16 Ast[3][2048];   // 12 KB
    __align__(16) _Float16 Bst[3][2048];   // 12 KB
  } sm;
  const int bch = blockIdx.x;
  const int r0p = blockIdx.y * 64;
  const int t = threadIdx.x;
  const int wv = t >> 6, lane = t & 63;
  const int colr = lane & 15, quad = lane >> 4;
  const int h = bch & 7, bc = bch >> 3, c = bc & 1;

  const _Float16* Asrc = x1 + ((size_t)bc*NN + r0p + wv*16 + colr)*512 + quad*8;
  const _Float16* Bsrc = w2T + (size_t)(c*HH + h)*32768 + wv*512 + lane*8;

  f32x4 acc[4];
  #pragma unroll
  for (int ft = 0; ft < 4; ++ft) acc[ft] = (f32x4){0.f,0.f,0.f,0.f};

#define STAGE_P(tt, slot) { \
    gl_lds16(Asrc + (tt)*32,           &sm.Ast[slot][wv*512]); \
    gl_lds16(Bsrc + (size_t)(tt)*2048, &sm.Bst[slot][wv*512]); }

  STAGE_P(0, 0);
  STAGE_P(1, 1);

  #pragma unroll
  for (int ks = 0; ks < 16; ++ks) {
    if (ks < 15) asm volatile("s_waitcnt vmcnt(2)" ::: "memory");   // pair(ks) landed
    else         asm volatile("s_waitcnt vmcnt(0)" ::: "memory");
    __builtin_amdgcn_s_barrier();
    if (ks < 14) STAGE_P(ks + 2, (ks + 2) % 3);

    const f16x8 Af = *(const f16x8*)&sm.Ast[ks % 3][wv*512 + lane*8];
    f16x8 Bc[4];
    #pragma unroll
    for (int ft = 0; ft < 4; ++ft)
      Bc[ft] = *(const f16x8*)&sm.Bst[ks % 3][ft*512 + lane*8];
    asm volatile("s_waitcnt lgkmcnt(0)" ::: "memory");
    __builtin_amdgcn_sched_barrier(0);

    __builtin_amdgcn_s_setprio(1);
    #pragma unroll
    for (int ft = 0; ft < 4; ++ft)
      acc[ft] = __builtin_amdgcn_mfma_f32_16x16x32_f16(Af, Bc[ft], acc[ft], 0, 0, 0);
    __builtin_amdgcn_s_setprio(0);
  }
#undef STAGE_P

  // epilogue: tanh scores over all 64 f (in-wave) + permuted HpT2 write
  float af[4], bfv[4];
  #pragma unroll
  for (int ft = 0; ft < 4; ++ft) {
    af[ft]  = asrc2[(c*HH + h)*64 + ft*16 + colr];
    bfv[ft] = adst2[(c*HH + h)*64 + ft*16 + colr];
  }
  #pragma unroll
  for (int i = 0; i < 4; ++i) {
    float ps = 0.f, pd = 0.f;
    #pragma unroll
    for (int ft = 0; ft < 4; ++ft) {
      const float v = acc[ft][i];
      const float ex = __expf(2.f*v);
      const float th = 1.f - 2.f/(ex + 1.f);   // tanh(v)
      ps += th * af[ft]; pd += th * bfv[ft];
    }
    #pragma unroll
    for (int off = 1; off < 16; off <<= 1) {
      ps += __shfl_xor(ps, off);
      pd += __shfl_xor(pd, off);
    }
    if (colr == 0) {
      s2[(size_t)bch*NN + r0p + wv*16 + quad*4 + i] = ps * LOG2E;
      d2[(size_t)bch*NN + r0p + wv*16 + quad*4 + i] = pd * LOG2E;
    }
  }
  _Float16* H2 = HpT2 + (size_t)bch*65536 + (size_t)((r0p >> 5) + (wv >> 1))*2048;
  const int cb = (wv & 1)*2 + (quad >> 1);
  #pragma unroll
  for (int ft = 0; ft < 4; ++ft) {
    f16x4 hv;
    #pragma unroll
    for (int i = 0; i < 4; ++i) hv[i] = (_Float16)acc[ft][i];
    const int chunk = ft*64 + cb*16 + colr;
    *(f16x4*)(H2 + chunk*8 + (quad & 1)*4) = hv;
  }
}

// ---------------- Mean over heads (f16 in, /8 already folded) -> fp32 out ----------
__global__ __launch_bounds__(256) void reduce_heads(
    const _Float16* __restrict__ out2, float* __restrict__ out)
{
  const int o = blockIdx.x*256 + threadIdx.x;
  const int f = o & 63;
  const int n = (o >> 6) & (NN - 1);
  const int bc = o >> 16;
  float acc = 0.f;
  #pragma unroll
  for (int h = 0; h < HH; ++h)
    acc += (float)out2[(((size_t)bc*HH + h)*NN + n)*64 + f];
  out[o] = acc;
}

extern "C" void kernel_launch(void* const* d_in, const int* in_sizes, int n_in,
                              void* d_out, int out_size, void* d_ws, size_t ws_size,
                              hipStream_t stream)
{
  const float* x   = (const float*)d_in[0];
  const int*   adj = (const int*)d_in[1];
  const float* w1  = (const float*)d_in[2];
  const float* as1 = (const float*)d_in[3];
  const float* ad1 = (const float*)d_in[4];
  const float* w2  = (const float*)d_in[5];
  const float* as2 = (const float*)d_in[6];
  const float* ad2 = (const float*)d_in[7];

  char* w8 = (char*)d_ws;
  _Float16* HpT  = (_Float16*)(w8);                         // 4 MB  permuted tiles
  _Float16* HpT2 = (_Float16*)(w8 + (4u<<20));              // 4 MB  permuted tiles
  _Float16* w2T  = (_Float16*)(w8 + (8u<<20));              // 1 MB  permuted tiles
  float* s_v  = (float*)(w8 + (10u<<20));                   // 128 KB (log2e-scaled)
  float* d_v  = (float*)(w8 + (10u<<20) + SVN*4);           // 128 KB
  float* s2_v = (float*)(w8 + (10u<<20) + SVN*8);           // 128 KB
  float* d2_v = (float*)(w8 + (10u<<20) + SVN*12);          // 128 KB
  unsigned long long* bmg = (unsigned long long*)(w8 + (10u<<20) + SVN*16);  // 256 KB
  _Float16* x1g = (_Float16*)(w8 + (16u<<20));              // 4 MB  [bc][N][512]
  _Float16* XB  = (_Float16*)(w8 + (20u<<20));              // 4 MB  [bch][N][64]

  proj1_fused<<<1408, 256, 0, stream>>>(x, adj, w1, w2, as1, ad1, w2T, bmg, HpT, s_v, d_v);
  attn_coop<1><<<dim3(BCHN, NN/64), 256, 0, stream>>>(HpT, s_v, d_v, bmg, x1g);
  proj2_coop<<<dim3(BCHN, NN/64), 256, 0, stream>>>(x1g, w2T, as2, ad2, HpT2, s2_v, d2_v);
  attn_coop<2><<<dim3(BCHN, NN/64), 256, 0, stream>>>(HpT2, s2_v, d2_v, bmg, XB);
  reduce_heads<<<dim3((unsigned)(out_size/256)), 256, 0, stream>>>(XB, (float*)d_out);
}